// Round 1
// baseline (235.220 us; speedup 1.0000x reference)
//
#include <hip/hip_runtime.h>
#include <hip/hip_fp16.h>
#include <math.h>

#define HW 1024
#define EPSV 1e-5f

typedef unsigned int uint;
typedef unsigned short ushort;
typedef __attribute__((ext_vector_type(8))) short short8;
typedef __attribute__((ext_vector_type(8))) _Float16 half8;
typedef __attribute__((ext_vector_type(4))) float floatx4;

// ---------------- ws layout (float offsets), no aliasing ---------------------------
static const size_t BOFF = 0;         // 36864   fp16 Boff[tap][n32][c256]
static const size_t BD   = 36864;     // 147456  fp16 Bd[oc][tap*256+c]
static const size_t BQ   = 184320;    // 131072  bf16 Bq[par][kstep][quad][n][8] (frag order)
static const size_t XT   = 315392;    // 2097152 fp16 xT[b][p][c]
static const size_t OFFB = 2412544;   // 524288  off [b][pix][32] fp32 (direct-stored)
static const size_t ST1  = 2936832;   // 1024: BN1 sum/sq, 4 striped copies of 256
static const size_t ST2  = 2937856;   // 4096: BN2 sum/sq, 16 striped copies of 256
static const size_t YP   = 2941952;   // 4194304 floats = bf16 y_part[4][pix][oc]
static const size_t YSUM = 7136256;   // 1048576 floats = bf16 ysum[pix][oc]
static const size_t YBN  = 8184832;   // 1048576 floats = bf16 ybn[pix][oc]
static const size_t OB   = 9233408;   // 4194304 floats = bf16 O[b][par][pix][oc]
// total = 13427712 floats = 53.7 MB

__device__ inline ushort f2bf(float f) {
  uint u = __builtin_bit_cast(uint, f);
  uint r = (u + 0x7FFFu + ((u >> 16) & 1u)) >> 16;
  return (ushort)r;
}
__device__ inline float b2f(ushort u) {
  return __builtin_bit_cast(float, ((uint)u) << 16);
}

// ---------------- 1. prep + xT + zero stats ---------------------------------------
__global__ __launch_bounds__(256) void prep_xt_kernel(const float* __restrict__ x,
                                                      const float* __restrict__ w_off,
                                                      const float* __restrict__ w_dcn,
                                                      const float* __restrict__ w_up,
                                                      float* __restrict__ ws) {
  __shared__ float tile[64 * 65];
  int blk = blockIdx.x;
  int tid = threadIdx.x;
  if (blk < 1024) {
    // xT: x[b][c][p] fp32 -> xT[b][p][c] fp16
    int b = blk >> 6, pt = (blk >> 2) & 15, cc = blk & 3;
    int p0 = pt * 64, c0 = cc * 64;
    int pp = tid & 63, ci = tid >> 6;
#pragma unroll
    for (int it = 0; it < 16; ++it) {
      int c = it * 4 + ci;
      tile[c * 65 + pp] = x[((size_t)(b * 256 + c0 + c)) * HW + p0 + pp];
    }
    __syncthreads();
    int cp = tid & 31, pp2 = tid >> 5;
    uint* xtu = (uint*)(ws + XT);
#pragma unroll
    for (int it = 0; it < 8; ++it) {
      int p = it * 8 + pp2;
      __half2 h = __floats2half2_rn(tile[(2 * cp) * 65 + p], tile[(2 * cp + 1) * 65 + p]);
      xtu[(size_t)(b * 1024 + p0 + p) * 128 + cc * 32 + cp] = __builtin_bit_cast(uint, h);
    }
  } else if (blk < 3488) {
    int i = (blk - 1024) * 256 + tid;
    if (i < 73728) {
      // Boff[tap][n][c], zero-padded n>=27
      int c = i & 255; int n = (i >> 8) & 31; int tap = i >> 13;
      float v = (n < 27) ? w_off[((size_t)n * 256 + c) * 9 + tap] : 0.f;
      ((__half*)(ws + BOFF))[i] = __float2half(v);
    } else if (i < 73728 + 294912) {
      int d = i - 73728;            // d = oc*2304 + tap*256 + c
      int oc = d / 2304; int k = d % 2304;
      int tap = k >> 8; int c = k & 255;
      ((__half*)(ws + BD))[d] = __float2half(w_dcn[((size_t)oc * 256 + c) * 9 + tap]);
    } else if (i < 73728 + 294912 + 262144) {
      // Bq[par][kstep][quad][n][8] bf16, fragment-ordered for direct global reads
      int d = i - (73728 + 294912);
      int j = d & 7; int n = (d >> 3) & 127; int quad = (d >> 10) & 3;
      int kstep = (d >> 12) & 15; int par = d >> 16;
      int k = kstep * 32 + quad * 8 + j;
      int t4 = k >> 7; int c = k & 127;
      int ty = t4 >> 1, tx = t4 & 1;
      int pu = par >> 1, pv = par & 1;
      int ky = (1 - pu) + 2 * ty, kx = (1 - pv) + 2 * tx;
      float v = w_up[((size_t)c * 128 + n) * 16 + ky * 4 + kx];
      ((ushort*)(ws + BQ))[d] = f2bf(v);
    }
  } else {
    int i = (blk - 3488) * 256 + tid;
    if (i < 5120) ws[ST1 + i] = 0.f;           // ST1(1024)+ST2(4096)
  }
}

// ---------------- 2. offset conv, full-K per block, direct store, dbuf A -----------
__global__ __launch_bounds__(256) void offconv_mfma_kernel(const __half* __restrict__ xt,
                                                           const __half* __restrict__ boff,
                                                           float* __restrict__ off) {
  __shared__ short As[2][64 * 136];   // [(cs*32+row)][136], 2 buffers
  int blk = blockIdx.x;
  int pt = blk & 31, b = blk >> 5;
  int P0 = pt * 32;
  int tid = threadIdx.x;
  int wid = tid >> 6, lane = tid & 63, lr = lane & 15, quad = lane >> 4;
  int m_w = (wid & 1) * 16, n_w = (wid >> 1) * 16;
  int arow = tid >> 3, aseg = tid & 7;       // 32 rows x 8 segs of 32 halves
  int ldsrow = (aseg >> 2) * 32 + arow;      // stack upper 128 ch as rows 32..63
  int lcol = (aseg & 3) * 32;
  int pix = P0 + arow; int h = pix >> 5, w = pix & 31;
  const __half* xb = xt + (size_t)b * 1024 * 256 + aseg * 32;
  const __half* bb = boff + (size_t)(n_w + lr) * 256 + quad * 8;

  floatx4 acc = (floatx4)0.f;

  float4 a0, a1, a2, a3;
  auto OGATHER = [&](int tap) {
    int ty = tap / 3, tx = tap % 3;
    int yy = h + ty - 1, xx = w + tx - 1;
    bool valid = (yy >= 0) && (yy < 32) && (xx >= 0) && (xx < 32);
    int pos = min(max(yy, 0), 31) * 32 + min(max(xx, 0), 31);
    const float4* ga = (const float4*)(xb + (size_t)pos * 256);
    a0 = ga[0]; a1 = ga[1]; a2 = ga[2]; a3 = ga[3];
    if (!valid) {
      a0 = make_float4(0.f, 0.f, 0.f, 0.f);
      a1 = a0; a2 = a0; a3 = a0;
    }
  };
  auto OSTORE = [&](int buf) {
    float4* qa = (float4*)(As[buf] + ldsrow * 136 + lcol);
    qa[0] = a0; qa[1] = a1; qa[2] = a2; qa[3] = a3;
  };

  OGATHER(0);
  OSTORE(0);
  __syncthreads();
#pragma unroll
  for (int tap = 0; tap < 9; ++tap) {
    int buf = tap & 1;
    if (tap < 8) OGATHER(tap + 1);           // loads issue before MFMA cluster
    const __half* brow = bb + (size_t)(tap * 32) * 256;
#pragma unroll
    for (int k2 = 0; k2 < 8; ++k2) {
      half8 af = *(const half8*)(As[buf] + ((k2 >> 2) * 32 + m_w + lr) * 136 + (k2 & 3) * 32 + quad * 8);
      half8 bf = *(const half8*)(brow + k2 * 32);
      acc = __builtin_amdgcn_mfma_f32_16x16x32_f16(af, bf, acc, 0, 0, 0);
    }
    if (tap < 8) OSTORE(buf ^ 1);
    __syncthreads();
  }
  int n = n_w + lr;
#pragma unroll
  for (int r = 0; r < 4; ++r) {
    int m = m_w + quad * 4 + r;
    off[((size_t)(b * 1024 + P0 + m)) * 32 + n] = acc[r];
  }
}

// ---------------- 3. deformable conv, dbuf A, direct-global B frags ----------------
__global__ __launch_bounds__(256) void deform_mfma_kernel(const __half* __restrict__ xt,
                                                          const float* __restrict__ off,
                                                          const float* __restrict__ b_off,
                                                          const __half* __restrict__ bd,
                                                          ushort* __restrict__ y_part) {
  __shared__ short As[2][64 * 72];
  int blk = blockIdx.x;
  int ptile = blk & 15, cs = (blk >> 4) & 3, b = blk >> 6;
  int tid = threadIdx.x;
  int wid = tid >> 6, lane = tid & 63, lr = lane & 15, quad = lane >> 4;
  int m_w = (wid & 1) * 32, n_w = (wid >> 1) * 64;
  int P0 = ptile * 64;
  int pix_l = tid >> 2, cseg = tid & 3;   // 64 px x 16-ch segs
  int pix = P0 + pix_l;
  int h = pix >> 5, w = pix & 31;
  const float* offb = off + (size_t)(b * 1024 + pix) * 32;
  const __half* xb = xt + (size_t)b * 1024 * 256 + cs * 64 + cseg * 16;
  const __half* bdb = bd + (size_t)(n_w + lr) * 2304 + cs * 64 + quad * 8;

  floatx4 acc[2][4];
#pragma unroll
  for (int mi = 0; mi < 2; ++mi)
#pragma unroll
    for (int ni = 0; ni < 4; ++ni) acc[mi][ni] = (floatx4)0.f;

  uint4 q[4][2];
  __half2 w2[4];
  float4 f0, f1;

  auto DGATHER = [&](int tap) {
    float dy = offb[2 * tap] + b_off[2 * tap];
    float dx = offb[2 * tap + 1] + b_off[2 * tap + 1];
    float mraw = offb[18 + tap] + b_off[18 + tap];
    float mm = 1.f / (1.f + __expf(-mraw));
    float py = (float)(h + tap / 3 - 1) + dy;
    float px = (float)(w + tap % 3 - 1) + dx;
    float y0f = floorf(py), x0f = floorf(px);
    float wy = py - y0f, wx = px - x0f;
    int y0 = (int)y0f, x0 = (int)x0f;
    float cw[4] = {(1.f - wy) * (1.f - wx), (1.f - wy) * wx, wy * (1.f - wx), wy * wx};
#pragma unroll
    for (int t = 0; t < 4; ++t) {
      int yy = y0 + (t >> 1), xx = x0 + (t & 1);
      bool v = (yy >= 0) && (yy <= 31) && (xx >= 0) && (xx <= 31);
      int yc = min(max(yy, 0), 31), xc = min(max(xx, 0), 31);
      const uint4* xr = (const uint4*)(xb + (size_t)(yc * 32 + xc) * 256);
      q[t][0] = xr[0]; q[t][1] = xr[1];
      w2[t] = __float2half2_rn(v ? cw[t] * mm : 0.f);
    }
  };
  auto DINTERP = [&]() {
    __half2 hacc[8];
#pragma unroll
    for (int j = 0; j < 8; ++j) hacc[j] = __float2half2_rn(0.f);
#pragma unroll
    for (int t = 0; t < 4; ++t) {
      uint qa[8] = {q[t][0].x, q[t][0].y, q[t][0].z, q[t][0].w,
                    q[t][1].x, q[t][1].y, q[t][1].z, q[t][1].w};
#pragma unroll
      for (int j = 0; j < 8; ++j)
        hacc[j] = __hfma2(w2[t], __builtin_bit_cast(__half2, qa[j]), hacc[j]);
    }
    f0.x = __builtin_bit_cast(float, hacc[0]);
    f0.y = __builtin_bit_cast(float, hacc[1]);
    f0.z = __builtin_bit_cast(float, hacc[2]);
    f0.w = __builtin_bit_cast(float, hacc[3]);
    f1.x = __builtin_bit_cast(float, hacc[4]);
    f1.y = __builtin_bit_cast(float, hacc[5]);
    f1.z = __builtin_bit_cast(float, hacc[6]);
    f1.w = __builtin_bit_cast(float, hacc[7]);
  };
  auto DSTORE = [&](int buf) {
    float4* qa2 = (float4*)(As[buf] + pix_l * 72 + cseg * 16);
    qa2[0] = f0; qa2[1] = f1;
  };

  DGATHER(0);
  DINTERP();
  DSTORE(0);
  __syncthreads();
#pragma unroll 1
  for (int tap = 0; tap < 9; ++tap) {
    int buf = tap & 1;
    if (tap < 8) DGATHER(tap + 1);          // next-tap gathers issue before MFMA
#pragma unroll
    for (int k2 = 0; k2 < 2; ++k2) {
      half8 af[2], bf[4];
#pragma unroll
      for (int mi = 0; mi < 2; ++mi)
        af[mi] = *(const half8*)(As[buf] + (m_w + mi * 16 + lr) * 72 + k2 * 32 + quad * 8);
#pragma unroll
      for (int ni = 0; ni < 4; ++ni)
        bf[ni] = *(const half8*)(bdb + (size_t)ni * 16 * 2304 + tap * 256 + k2 * 32);
#pragma unroll
      for (int mi = 0; mi < 2; ++mi)
#pragma unroll
        for (int ni = 0; ni < 4; ++ni)
          acc[mi][ni] = __builtin_amdgcn_mfma_f32_16x16x32_f16(af[mi], bf[ni], acc[mi][ni], 0, 0, 0);
    }
    if (tap < 8) {
      DINTERP();
      DSTORE(buf ^ 1);
    }
    __syncthreads();
  }
  ushort* yp = y_part + (size_t)cs * 2097152 + ((size_t)(b * 1024 + P0)) * 128;
#pragma unroll
  for (int mi = 0; mi < 2; ++mi) {
#pragma unroll
    for (int r = 0; r < 4; ++r) {
      int m = m_w + mi * 16 + quad * 4 + r;
      ushort* orow = yp + (size_t)m * 128;
#pragma unroll
      for (int ni = 0; ni < 4; ++ni)
        orow[n_w + ni * 16 + lr] = f2bf(acc[mi][ni][r]);
    }
  }
}

// ---------------- 4. yred: 4 bf16 partials + bias -> bf16 ysum; striped BN1 atomics
__global__ __launch_bounds__(256) void yred_kernel(const ushort* __restrict__ yp,
                                                   const float* __restrict__ b_dcn,
                                                   ushort* __restrict__ ysum,
                                                   float* __restrict__ st1) {
  int blk = blockIdx.x; int tid = threadIdx.x;
  int oc = tid & 127, rh = tid >> 7;
  float bias = b_dcn[oc];
  float s = 0.f, sq = 0.f;
  for (int r = rh; r < 128; r += 2) {
    size_t idx = ((size_t)(blk * 128 + r)) * 128 + oc;
    float v = b2f(yp[idx]) + b2f(yp[2097152 + idx]) + b2f(yp[4194304 + idx])
            + b2f(yp[6291456 + idx]) + bias;
    ysum[idx] = f2bf(v);
    s += v; sq = fmaf(v, v, sq);
  }
  __shared__ float ls[256], lq[256];
  ls[tid] = s; lq[tid] = sq; __syncthreads();
  if (tid < 128) {
    float* dst = st1 + (blk & 3) * 256;
    atomicAdd(&dst[tid], ls[tid] + ls[tid + 128]);
    atomicAdd(&dst[128 + tid], lq[tid] + lq[tid + 128]);
  }
}

// ---------------- 5. ybn: BN1+ReLU on bf16 ysum -> bf16 ybn ------------------------
__global__ __launch_bounds__(256) void ybn_kernel(const ushort* __restrict__ ysum,
                                                  const float* __restrict__ st1,
                                                  const float* __restrict__ g1,
                                                  const float* __restrict__ bt1,
                                                  ushort* __restrict__ ybn) {
  __shared__ float scs[128], shs[128];
  int tid = threadIdx.x;
  if (tid < 128) {
    float s  = st1[tid] + st1[256 + tid] + st1[512 + tid] + st1[768 + tid];
    float sq = st1[128 + tid] + st1[384 + tid] + st1[640 + tid] + st1[896 + tid];
    float mean = s / 16384.f;
    float var = sq / 16384.f - mean * mean;
    float sc = g1[tid] * rsqrtf(var + EPSV);
    scs[tid] = sc;
    shs[tid] = fmaf(-mean, sc, bt1[tid]);
  }
  __syncthreads();
  int i8 = blockIdx.x * 256 + tid;
  size_t i = (size_t)i8 * 8;
  int oc = (int)(i & 127);
  uint4 pv = *(const uint4*)(ysum + i);
  uint words[4] = {pv.x, pv.y, pv.z, pv.w};
  uint owords[4];
#pragma unroll
  for (int j = 0; j < 4; ++j) {
    ushort u0 = (ushort)(words[j] & 0xFFFFu);
    ushort u1 = (ushort)(words[j] >> 16);
    int c0 = oc + 2 * j, c1 = oc + 2 * j + 1;
    float v0 = fmaxf(fmaf(b2f(u0), scs[c0], shs[c0]), 0.f);
    float v1 = fmaxf(fmaf(b2f(u1), scs[c1], shs[c1]), 0.f);
    owords[j] = (uint)f2bf(v0) | ((uint)f2bf(v1) << 16);
  }
  *(uint4*)(ybn + i) = make_uint4(owords[0], owords[1], owords[2], owords[3]);
}

// ---------------- 6. deconv: barrier-free register GEMM, bf16 O output -------------
__global__ __launch_bounds__(256) void deconv_mfma_kernel(const ushort* __restrict__ ybn,
                                                          const ushort* __restrict__ bq,
                                                          ushort* __restrict__ O,
                                                          float* __restrict__ st2) {
  int blk = blockIdx.x;
  int pt = blk & 15, par = (blk >> 4) & 3, b = blk >> 6;
  int pu = par >> 1, pv = par & 1;
  int tid = threadIdx.x;
  int wid = tid >> 6, lane = tid & 63, lr = lane & 15, quad = lane >> 4;
  int P0 = pt * 64;
  int hh[4], ww[4];
#pragma unroll
  for (int mi = 0; mi < 4; ++mi) {
    int p = P0 + mi * 16 + lr;
    hh[mi] = p >> 5; ww[mi] = p & 31;
  }

  floatx4 acc[4][2];
#pragma unroll
  for (int mi = 0; mi < 4; ++mi)
#pragma unroll
    for (int ni = 0; ni < 2; ++ni) acc[mi][ni] = (floatx4)0.f;

  const ushort* ybb = ybn + (size_t)b * 1024 * 128;
  const ushort* bqb = bq + par * 65536 + quad * 1024 + (wid * 32 + lr) * 8;

#pragma unroll
  for (int tap = 0; tap < 4; ++tap) {
    int ty = tap >> 1, tx = tap & 1;
    int ab[4]; bool val[4];
#pragma unroll
    for (int mi = 0; mi < 4; ++mi) {
      int i = hh[mi] + pu - ty, j = ww[mi] + pv - tx;
      val[mi] = (i >= 0) && (i <= 31) && (j >= 0) && (j <= 31);
      int pos = min(max(i, 0), 31) * 32 + min(max(j, 0), 31);
      ab[mi] = pos * 128;
    }
#pragma unroll
    for (int k2 = 0; k2 < 4; ++k2) {
      int kstep = tap * 4 + k2;
      int c0 = k2 * 32 + quad * 8;
      short8 bf[2];
#pragma unroll
      for (int ni = 0; ni < 2; ++ni)
        bf[ni] = *(const short8*)(bqb + kstep * 4096 + ni * 128);
      short8 af[4];
#pragma unroll
      for (int mi = 0; mi < 4; ++mi) {
        short8 a = *(const short8*)(ybb + ab[mi] + c0);
        af[mi] = val[mi] ? a : (short8)0;
      }
#pragma unroll
      for (int mi = 0; mi < 4; ++mi)
#pragma unroll
        for (int ni = 0; ni < 2; ++ni)
          acc[mi][ni] = __builtin_amdgcn_mfma_f32_16x16x32_bf16(af[mi], bf[ni], acc[mi][ni], 0, 0, 0);
    }
  }
  size_t obase = (size_t)(b * 4 + par) * 1024 * 128;
#pragma unroll
  for (int mi = 0; mi < 4; ++mi) {
#pragma unroll
    for (int r = 0; r < 4; ++r) {
      int m = mi * 16 + quad * 4 + r;
      ushort* orow = O + obase + (size_t)(P0 + m) * 128 + wid * 32;
#pragma unroll
      for (int ni = 0; ni < 2; ++ni)
        orow[ni * 16 + lr] = f2bf(acc[mi][ni][r]);
    }
  }
  float sn[2], qn[2];
#pragma unroll
  for (int ni = 0; ni < 2; ++ni) {
    float s = 0.f, q = 0.f;
#pragma unroll
    for (int mi = 0; mi < 4; ++mi)
#pragma unroll
      for (int r = 0; r < 4; ++r) {
        float v = acc[mi][ni][r];
        s += v; q = fmaf(v, v, q);
      }
    sn[ni] = s; qn[ni] = q;
  }
#pragma unroll
  for (int ni = 0; ni < 2; ++ni) {
    sn[ni] += __shfl_xor(sn[ni], 16);
    sn[ni] += __shfl_xor(sn[ni], 32);
    qn[ni] += __shfl_xor(qn[ni], 16);
    qn[ni] += __shfl_xor(qn[ni], 32);
  }
  if (lane < 16) {
    float* dst = st2 + (blk & 15) * 256;
#pragma unroll
    for (int ni = 0; ni < 2; ++ni) {
      atomicAdd(&dst[wid * 32 + ni * 16 + lr], sn[ni]);
      atomicAdd(&dst[128 + wid * 32 + ni * 16 + lr], qn[ni]);
    }
  }
}

// ---------------- 7. bnout: BN2 from 16 striped stats + transpose to NCHW ----------
__global__ __launch_bounds__(256) void bnout_kernel(const ushort* __restrict__ O,
                                                    const float* __restrict__ st2,
                                                    const float* __restrict__ g2,
                                                    const float* __restrict__ bt2,
                                                    float* __restrict__ out) {
  __shared__ float tile[128 * 33];
  __shared__ float scs[128], shs[128];
  int blk = blockIdx.x;
  int uu = blk & 31, par = (blk >> 5) & 3, b = blk >> 7;
  int pu = par >> 1, pv = par & 1;
  int tid = threadIdx.x;
  if (tid < 128) {
    float s = 0.f, sq = 0.f;
#pragma unroll
    for (int c = 0; c < 16; ++c) {
      s += st2[c * 256 + tid];
      sq += st2[c * 256 + 128 + tid];
    }
    float mean = s / 65536.f;
    float var = sq / 65536.f - mean * mean;
    float sc = g2[tid] * rsqrtf(var + EPSV);
    scs[tid] = sc;
    shs[tid] = fmaf(-mean, sc, bt2[tid]);
  }
  __syncthreads();
#pragma unroll 4
  for (int it = 0; it < 16; ++it) {
    int idx = it * 256 + tid;
    int vv = idx >> 7, oc = idx & 127;
    float v = b2f(O[((size_t)(b * 4 + par) * 1024 + uu * 32 + vv) * 128 + oc]);
    tile[oc * 33 + vv] = fmaxf(fmaf(v, scs[oc], shs[oc]), 0.f);
  }
  __syncthreads();
#pragma unroll 4
  for (int it = 0; it < 16; ++it) {
    int idx = it * 256 + tid;
    int oc = idx >> 5, vv = idx & 31;
    out[((size_t)b * 128 + oc) * 4096 + (2 * uu + pu) * 64 + 2 * vv + pv] = tile[oc * 33 + vv];
  }
}

extern "C" void kernel_launch(void* const* d_in, const int* in_sizes, int n_in,
                              void* d_out, int out_size, void* d_ws, size_t ws_size,
                              hipStream_t stream) {
  const float* x     = (const float*)d_in[0];
  const float* w_off = (const float*)d_in[1];
  const float* b_off = (const float*)d_in[2];
  const float* w_dcn = (const float*)d_in[3];
  const float* b_dcn = (const float*)d_in[4];
  const float* g1    = (const float*)d_in[5];
  const float* bt1   = (const float*)d_in[6];
  const float* w_up  = (const float*)d_in[7];
  const float* g2    = (const float*)d_in[8];
  const float* bt2   = (const float*)d_in[9];
  float* ws  = (float*)d_ws;
  float* out = (float*)d_out;

  prep_xt_kernel<<<3508, 256, 0, stream>>>(x, w_off, w_dcn, w_up, ws);
  offconv_mfma_kernel<<<512, 256, 0, stream>>>((const __half*)(ws + XT),
                                               (const __half*)(ws + BOFF), ws + OFFB);
  deform_mfma_kernel<<<1024, 256, 0, stream>>>((const __half*)(ws + XT), ws + OFFB, b_off,
                                               (const __half*)(ws + BD), (ushort*)(ws + YP));
  yred_kernel<<<128, 256, 0, stream>>>((const ushort*)(ws + YP), b_dcn,
                                       (ushort*)(ws + YSUM), ws + ST1);
  ybn_kernel<<<1024, 256, 0, stream>>>((const ushort*)(ws + YSUM), ws + ST1, g1, bt1,
                                       (ushort*)(ws + YBN));
  deconv_mfma_kernel<<<1024, 256, 0, stream>>>((const ushort*)(ws + YBN),
                                               (const ushort*)(ws + BQ),
                                               (ushort*)(ws + OB), ws + ST2);
  bnout_kernel<<<2048, 256, 0, stream>>>((const ushort*)(ws + OB), ws + ST2, g2, bt2, out);
}

// Round 2
// 229.945 us; speedup vs baseline: 1.0229x; 1.0229x over previous
//
#include <hip/hip_runtime.h>
#include <hip/hip_fp16.h>
#include <math.h>

#define HW 1024
#define EPSV 1e-5f

typedef unsigned int uint;
typedef unsigned short ushort;
typedef __attribute__((ext_vector_type(8))) short short8;
typedef __attribute__((ext_vector_type(8))) _Float16 half8;
typedef __attribute__((ext_vector_type(4))) float floatx4;

// ---------------- ws layout (float offsets), no aliasing ---------------------------
static const size_t BOFF = 0;         // 36864   fp16 Boff[tap][n32][c256]
static const size_t BD   = 36864;     // 147456  fp16 Bd[oc][tap*256+c]
static const size_t BQ   = 184320;    // 131072  bf16 Bq[par][kstep][quad][n][8] (frag order)
static const size_t XT   = 315392;    // 2097152 fp16 xT[b][p][c]
static const size_t OFFB = 2412544;   // 524288  off [b][pix][32] fp32 (direct-stored)
static const size_t ST1  = 2936832;   // 1024: BN1 sum/sq, 4 striped copies of 256
static const size_t ST2  = 2937856;   // 4096: BN2 sum/sq, 16 striped copies of 256
static const size_t YP   = 2941952;   // 4194304 floats = bf16 y_part[4][pix][oc]
static const size_t YSUM = 7136256;   // 1048576 floats = bf16 ysum[pix][oc]
static const size_t YBN  = 8184832;   // 1048576 floats = bf16 ybn[pix][oc]
static const size_t OB   = 9233408;   // 4194304 floats = bf16 O[b][par][pix][oc]
// total = 13427712 floats = 53.7 MB

__device__ inline ushort f2bf(float f) {
  uint u = __builtin_bit_cast(uint, f);
  uint r = (u + 0x7FFFu + ((u >> 16) & 1u)) >> 16;
  return (ushort)r;
}
__device__ inline float b2f(ushort u) {
  return __builtin_bit_cast(float, ((uint)u) << 16);
}

// ---------------- 1. prep + xT + zero stats ---------------------------------------
// xT blocks remapped so image b is pinned to XCD b%8 (same pinning as consumers).
__global__ __launch_bounds__(256) void prep_xt_kernel(const float* __restrict__ x,
                                                      const float* __restrict__ w_off,
                                                      const float* __restrict__ w_dcn,
                                                      const float* __restrict__ w_up,
                                                      float* __restrict__ ws) {
  __shared__ float tile[64 * 65];
  int blk = blockIdx.x;
  int tid = threadIdx.x;
  if (blk < 1024) {
    // xT: x[b][c][p] fp32 -> xT[b][p][c] fp16
    int b = blk & 15, pt = (blk >> 4) & 15, cc = blk >> 8;
    int p0 = pt * 64, c0 = cc * 64;
    int pp = tid & 63, ci = tid >> 6;
#pragma unroll
    for (int it = 0; it < 16; ++it) {
      int c = it * 4 + ci;
      tile[c * 65 + pp] = x[((size_t)(b * 256 + c0 + c)) * HW + p0 + pp];
    }
    __syncthreads();
    int cp = tid & 31, pp2 = tid >> 5;
    uint* xtu = (uint*)(ws + XT);
#pragma unroll
    for (int it = 0; it < 8; ++it) {
      int p = it * 8 + pp2;
      __half2 h = __floats2half2_rn(tile[(2 * cp) * 65 + p], tile[(2 * cp + 1) * 65 + p]);
      xtu[(size_t)(b * 1024 + p0 + p) * 128 + cc * 32 + cp] = __builtin_bit_cast(uint, h);
    }
  } else if (blk < 3488) {
    int i = (blk - 1024) * 256 + tid;
    if (i < 73728) {
      // Boff[tap][n][c], zero-padded n>=27
      int c = i & 255; int n = (i >> 8) & 31; int tap = i >> 13;
      float v = (n < 27) ? w_off[((size_t)n * 256 + c) * 9 + tap] : 0.f;
      ((__half*)(ws + BOFF))[i] = __float2half(v);
    } else if (i < 73728 + 294912) {
      int d = i - 73728;            // d = oc*2304 + tap*256 + c
      int oc = d / 2304; int k = d % 2304;
      int tap = k >> 8; int c = k & 255;
      ((__half*)(ws + BD))[d] = __float2half(w_dcn[((size_t)oc * 256 + c) * 9 + tap]);
    } else if (i < 73728 + 294912 + 262144) {
      // Bq[par][kstep][quad][n][8] bf16, fragment-ordered for direct global reads
      int d = i - (73728 + 294912);
      int j = d & 7; int n = (d >> 3) & 127; int quad = (d >> 10) & 3;
      int kstep = (d >> 12) & 15; int par = d >> 16;
      int k = kstep * 32 + quad * 8 + j;
      int t4 = k >> 7; int c = k & 127;
      int ty = t4 >> 1, tx = t4 & 1;
      int pu = par >> 1, pv = par & 1;
      int ky = (1 - pu) + 2 * ty, kx = (1 - pv) + 2 * tx;
      float v = w_up[((size_t)c * 128 + n) * 16 + ky * 4 + kx];
      ((ushort*)(ws + BQ))[d] = f2bf(v);
    }
  } else {
    int i = (blk - 3488) * 256 + tid;
    if (i < 5120) ws[ST1 + i] = 0.f;           // ST1(1024)+ST2(4096)
  }
}

// ---------------- 2. offset conv, full-K per block, direct store, dbuf A -----------
// b pinned to XCD via b = blk & 15.
__global__ __launch_bounds__(256) void offconv_mfma_kernel(const __half* __restrict__ xt,
                                                           const __half* __restrict__ boff,
                                                           float* __restrict__ off) {
  __shared__ short As[2][64 * 136];   // [(cs*32+row)][136], 2 buffers
  int blk = blockIdx.x;
  int b = blk & 15, pt = blk >> 4;
  int P0 = pt * 32;
  int tid = threadIdx.x;
  int wid = tid >> 6, lane = tid & 63, lr = lane & 15, quad = lane >> 4;
  int m_w = (wid & 1) * 16, n_w = (wid >> 1) * 16;
  int arow = tid >> 3, aseg = tid & 7;       // 32 rows x 8 segs of 32 halves
  int ldsrow = (aseg >> 2) * 32 + arow;      // stack upper 128 ch as rows 32..63
  int lcol = (aseg & 3) * 32;
  int pix = P0 + arow; int h = pix >> 5, w = pix & 31;
  const __half* xb = xt + (size_t)b * 1024 * 256 + aseg * 32;
  const __half* bb = boff + (size_t)(n_w + lr) * 256 + quad * 8;

  floatx4 acc = (floatx4)0.f;

  float4 a0, a1, a2, a3;
  auto OGATHER = [&](int tap) {
    int ty = tap / 3, tx = tap % 3;
    int yy = h + ty - 1, xx = w + tx - 1;
    bool valid = (yy >= 0) && (yy < 32) && (xx >= 0) && (xx < 32);
    int pos = min(max(yy, 0), 31) * 32 + min(max(xx, 0), 31);
    const float4* ga = (const float4*)(xb + (size_t)pos * 256);
    a0 = ga[0]; a1 = ga[1]; a2 = ga[2]; a3 = ga[3];
    if (!valid) {
      a0 = make_float4(0.f, 0.f, 0.f, 0.f);
      a1 = a0; a2 = a0; a3 = a0;
    }
  };
  auto OSTORE = [&](int buf) {
    float4* qa = (float4*)(As[buf] + ldsrow * 136 + lcol);
    qa[0] = a0; qa[1] = a1; qa[2] = a2; qa[3] = a3;
  };

  OGATHER(0);
  OSTORE(0);
  __syncthreads();
#pragma unroll
  for (int tap = 0; tap < 9; ++tap) {
    int buf = tap & 1;
    if (tap < 8) OGATHER(tap + 1);           // loads issue before MFMA cluster
    const __half* brow = bb + (size_t)(tap * 32) * 256;
#pragma unroll
    for (int k2 = 0; k2 < 8; ++k2) {
      half8 af = *(const half8*)(As[buf] + ((k2 >> 2) * 32 + m_w + lr) * 136 + (k2 & 3) * 32 + quad * 8);
      half8 bf = *(const half8*)(brow + k2 * 32);
      acc = __builtin_amdgcn_mfma_f32_16x16x32_f16(af, bf, acc, 0, 0, 0);
    }
    if (tap < 8) OSTORE(buf ^ 1);
    __syncthreads();
  }
  int n = n_w + lr;
#pragma unroll
  for (int r = 0; r < 4; ++r) {
    int m = m_w + quad * 4 + r;
    off[((size_t)(b * 1024 + P0 + m)) * 32 + n] = acc[r];
  }
}

// ---------------- 3. deformable conv: dbuf A (1 barrier/tap), reg-B prefetch -------
// Fully unrolled tap loop; B fragments live in registers, loaded one tap ahead.
// b pinned to XCD via b = blk & 15.
__global__ __launch_bounds__(256) void deform_mfma_kernel(const __half* __restrict__ xt,
                                                          const float* __restrict__ off,
                                                          const float* __restrict__ b_off,
                                                          const __half* __restrict__ bd,
                                                          ushort* __restrict__ y_part) {
  __shared__ short As[2][64 * 72];
  int blk = blockIdx.x;
  int b = blk & 15;
  int r = blk >> 4;
  int ptile = r & 15, cs = r >> 4;
  int tid = threadIdx.x;
  int wid = tid >> 6, lane = tid & 63, lr = lane & 15, quad = lane >> 4;
  int m_w = (wid & 1) * 32, n_w = (wid >> 1) * 64;
  int P0 = ptile * 64;
  int pix_l = tid >> 2, cseg = tid & 3;   // 64 px x 16-ch segs
  int pix = P0 + pix_l;
  int h = pix >> 5, w = pix & 31;
  const float* offb = off + (size_t)(b * 1024 + pix) * 32;
  const __half* xb = xt + (size_t)b * 1024 * 256 + cs * 64 + cseg * 16;
  const __half* bdb = bd + (size_t)(n_w + lr) * 2304 + cs * 64 + quad * 8;

  floatx4 acc[2][4];
#pragma unroll
  for (int mi = 0; mi < 2; ++mi)
#pragma unroll
    for (int ni = 0; ni < 4; ++ni) acc[mi][ni] = (floatx4)0.f;

  uint4 q[4][2];
  __half2 w2[4];
  float4 f0, f1;
  half8 bcur[8];

  auto DGATHER = [&](int tap) {
    float dy = offb[2 * tap] + b_off[2 * tap];
    float dx = offb[2 * tap + 1] + b_off[2 * tap + 1];
    float mraw = offb[18 + tap] + b_off[18 + tap];
    float mm = 1.f / (1.f + __expf(-mraw));
    float py = (float)(h + tap / 3 - 1) + dy;
    float px = (float)(w + tap % 3 - 1) + dx;
    float y0f = floorf(py), x0f = floorf(px);
    float wy = py - y0f, wx = px - x0f;
    int y0 = (int)y0f, x0 = (int)x0f;
    float cw[4] = {(1.f - wy) * (1.f - wx), (1.f - wy) * wx, wy * (1.f - wx), wy * wx};
#pragma unroll
    for (int t = 0; t < 4; ++t) {
      int yy = y0 + (t >> 1), xx = x0 + (t & 1);
      bool v = (yy >= 0) && (yy <= 31) && (xx >= 0) && (xx <= 31);
      int yc = min(max(yy, 0), 31), xc = min(max(xx, 0), 31);
      const uint4* xr = (const uint4*)(xb + (size_t)(yc * 32 + xc) * 256);
      q[t][0] = xr[0]; q[t][1] = xr[1];
      w2[t] = __float2half2_rn(v ? cw[t] * mm : 0.f);
    }
  };
  auto BLOAD = [&](int tap) {
#pragma unroll
    for (int ni = 0; ni < 4; ++ni)
#pragma unroll
      for (int k2 = 0; k2 < 2; ++k2)
        bcur[ni * 2 + k2] = *(const half8*)(bdb + (size_t)ni * 16 * 2304 + tap * 256 + k2 * 32);
  };
  auto DINTERP = [&]() {
    __half2 hacc[8];
#pragma unroll
    for (int j = 0; j < 8; ++j) hacc[j] = __float2half2_rn(0.f);
#pragma unroll
    for (int t = 0; t < 4; ++t) {
      uint qa[8] = {q[t][0].x, q[t][0].y, q[t][0].z, q[t][0].w,
                    q[t][1].x, q[t][1].y, q[t][1].z, q[t][1].w};
#pragma unroll
      for (int j = 0; j < 8; ++j)
        hacc[j] = __hfma2(w2[t], __builtin_bit_cast(__half2, qa[j]), hacc[j]);
    }
    f0.x = __builtin_bit_cast(float, hacc[0]);
    f0.y = __builtin_bit_cast(float, hacc[1]);
    f0.z = __builtin_bit_cast(float, hacc[2]);
    f0.w = __builtin_bit_cast(float, hacc[3]);
    f1.x = __builtin_bit_cast(float, hacc[4]);
    f1.y = __builtin_bit_cast(float, hacc[5]);
    f1.z = __builtin_bit_cast(float, hacc[6]);
    f1.w = __builtin_bit_cast(float, hacc[7]);
  };
  auto DSTORE = [&](int buf) {
    float4* qa2 = (float4*)(As[buf] + pix_l * 72 + cseg * 16);
    qa2[0] = f0; qa2[1] = f1;
  };

  DGATHER(0);
  BLOAD(0);
  DINTERP();
  DSTORE(0);
  __syncthreads();
#pragma unroll
  for (int tap = 0; tap < 9; ++tap) {
    int buf = tap & 1;
    if (tap < 8) DGATHER(tap + 1);          // next-tap gathers issue before MFMA
#pragma unroll
    for (int k2 = 0; k2 < 2; ++k2) {
      half8 af[2];
#pragma unroll
      for (int mi = 0; mi < 2; ++mi)
        af[mi] = *(const half8*)(As[buf] + (m_w + mi * 16 + lr) * 72 + k2 * 32 + quad * 8);
#pragma unroll
      for (int mi = 0; mi < 2; ++mi)
#pragma unroll
        for (int ni = 0; ni < 4; ++ni)
          acc[mi][ni] = __builtin_amdgcn_mfma_f32_16x16x32_f16(af[mi], bcur[ni * 2 + k2], acc[mi][ni], 0, 0, 0);
    }
    if (tap < 8) {
      BLOAD(tap + 1);                       // B for next tap: lands during interp+barrier
      DINTERP();
      DSTORE(buf ^ 1);
    }
    __syncthreads();
  }
  ushort* yp = y_part + (size_t)cs * 2097152 + ((size_t)(b * 1024 + P0)) * 128;
#pragma unroll
  for (int mi = 0; mi < 2; ++mi) {
#pragma unroll
    for (int r2 = 0; r2 < 4; ++r2) {
      int m = m_w + mi * 16 + quad * 4 + r2;
      ushort* orow = yp + (size_t)m * 128;
#pragma unroll
      for (int ni = 0; ni < 4; ++ni)
        orow[n_w + ni * 16 + lr] = f2bf(acc[mi][ni][r2]);
    }
  }
}

// ---------------- 4. yred: 4 bf16 partials + bias -> bf16 ysum; striped BN1 atomics
__global__ __launch_bounds__(256) void yred_kernel(const ushort* __restrict__ yp,
                                                   const float* __restrict__ b_dcn,
                                                   ushort* __restrict__ ysum,
                                                   float* __restrict__ st1) {
  int blk = blockIdx.x; int tid = threadIdx.x;
  int oc = tid & 127, rh = tid >> 7;
  float bias = b_dcn[oc];
  float s = 0.f, sq = 0.f;
  for (int r = rh; r < 128; r += 2) {
    size_t idx = ((size_t)(blk * 128 + r)) * 128 + oc;
    float v = b2f(yp[idx]) + b2f(yp[2097152 + idx]) + b2f(yp[4194304 + idx])
            + b2f(yp[6291456 + idx]) + bias;
    ysum[idx] = f2bf(v);
    s += v; sq = fmaf(v, v, sq);
  }
  __shared__ float ls[256], lq[256];
  ls[tid] = s; lq[tid] = sq; __syncthreads();
  if (tid < 128) {
    float* dst = st1 + (blk & 3) * 256;
    atomicAdd(&dst[tid], ls[tid] + ls[tid + 128]);
    atomicAdd(&dst[128 + tid], lq[tid] + lq[tid + 128]);
  }
}

// ---------------- 5. ybn: BN1+ReLU on bf16 ysum -> bf16 ybn ------------------------
__global__ __launch_bounds__(256) void ybn_kernel(const ushort* __restrict__ ysum,
                                                  const float* __restrict__ st1,
                                                  const float* __restrict__ g1,
                                                  const float* __restrict__ bt1,
                                                  ushort* __restrict__ ybn) {
  __shared__ float scs[128], shs[128];
  int tid = threadIdx.x;
  if (tid < 128) {
    float s  = st1[tid] + st1[256 + tid] + st1[512 + tid] + st1[768 + tid];
    float sq = st1[128 + tid] + st1[384 + tid] + st1[640 + tid] + st1[896 + tid];
    float mean = s / 16384.f;
    float var = sq / 16384.f - mean * mean;
    float sc = g1[tid] * rsqrtf(var + EPSV);
    scs[tid] = sc;
    shs[tid] = fmaf(-mean, sc, bt1[tid]);
  }
  __syncthreads();
  int i8 = blockIdx.x * 256 + tid;
  size_t i = (size_t)i8 * 8;
  int oc = (int)(i & 127);
  uint4 pv = *(const uint4*)(ysum + i);
  uint words[4] = {pv.x, pv.y, pv.z, pv.w};
  uint owords[4];
#pragma unroll
  for (int j = 0; j < 4; ++j) {
    ushort u0 = (ushort)(words[j] & 0xFFFFu);
    ushort u1 = (ushort)(words[j] >> 16);
    int c0 = oc + 2 * j, c1 = oc + 2 * j + 1;
    float v0 = fmaxf(fmaf(b2f(u0), scs[c0], shs[c0]), 0.f);
    float v1 = fmaxf(fmaf(b2f(u1), scs[c1], shs[c1]), 0.f);
    owords[j] = (uint)f2bf(v0) | ((uint)f2bf(v1) << 16);
  }
  *(uint4*)(ybn + i) = make_uint4(owords[0], owords[1], owords[2], owords[3]);
}

// ---------------- 6. deconv: barrier-free register GEMM, bf16 O output -------------
__global__ __launch_bounds__(256) void deconv_mfma_kernel(const ushort* __restrict__ ybn,
                                                          const ushort* __restrict__ bq,
                                                          ushort* __restrict__ O,
                                                          float* __restrict__ st2) {
  int blk = blockIdx.x;
  int pt = blk & 15, par = (blk >> 4) & 3, b = blk >> 6;
  int pu = par >> 1, pv = par & 1;
  int tid = threadIdx.x;
  int wid = tid >> 6, lane = tid & 63, lr = lane & 15, quad = lane >> 4;
  int P0 = pt * 64;
  int hh[4], ww[4];
#pragma unroll
  for (int mi = 0; mi < 4; ++mi) {
    int p = P0 + mi * 16 + lr;
    hh[mi] = p >> 5; ww[mi] = p & 31;
  }

  floatx4 acc[4][2];
#pragma unroll
  for (int mi = 0; mi < 4; ++mi)
#pragma unroll
    for (int ni = 0; ni < 2; ++ni) acc[mi][ni] = (floatx4)0.f;

  const ushort* ybb = ybn + (size_t)b * 1024 * 128;
  const ushort* bqb = bq + par * 65536 + quad * 1024 + (wid * 32 + lr) * 8;

#pragma unroll
  for (int tap = 0; tap < 4; ++tap) {
    int ty = tap >> 1, tx = tap & 1;
    int ab[4]; bool val[4];
#pragma unroll
    for (int mi = 0; mi < 4; ++mi) {
      int i = hh[mi] + pu - ty, j = ww[mi] + pv - tx;
      val[mi] = (i >= 0) && (i <= 31) && (j >= 0) && (j <= 31);
      int pos = min(max(i, 0), 31) * 32 + min(max(j, 0), 31);
      ab[mi] = pos * 128;
    }
#pragma unroll
    for (int k2 = 0; k2 < 4; ++k2) {
      int kstep = tap * 4 + k2;
      int c0 = k2 * 32 + quad * 8;
      short8 bf[2];
#pragma unroll
      for (int ni = 0; ni < 2; ++ni)
        bf[ni] = *(const short8*)(bqb + kstep * 4096 + ni * 128);
      short8 af[4];
#pragma unroll
      for (int mi = 0; mi < 4; ++mi) {
        short8 a = *(const short8*)(ybb + ab[mi] + c0);
        af[mi] = val[mi] ? a : (short8)0;
      }
#pragma unroll
      for (int mi = 0; mi < 4; ++mi)
#pragma unroll
        for (int ni = 0; ni < 2; ++ni)
          acc[mi][ni] = __builtin_amdgcn_mfma_f32_16x16x32_bf16(af[mi], bf[ni], acc[mi][ni], 0, 0, 0);
    }
  }
  size_t obase = (size_t)(b * 4 + par) * 1024 * 128;
#pragma unroll
  for (int mi = 0; mi < 4; ++mi) {
#pragma unroll
    for (int r = 0; r < 4; ++r) {
      int m = mi * 16 + quad * 4 + r;
      ushort* orow = O + obase + (size_t)(P0 + m) * 128 + wid * 32;
#pragma unroll
      for (int ni = 0; ni < 2; ++ni)
        orow[ni * 16 + lr] = f2bf(acc[mi][ni][r]);
    }
  }
  float sn[2], qn[2];
#pragma unroll
  for (int ni = 0; ni < 2; ++ni) {
    float s = 0.f, q = 0.f;
#pragma unroll
    for (int mi = 0; mi < 4; ++mi)
#pragma unroll
      for (int r = 0; r < 4; ++r) {
        float v = acc[mi][ni][r];
        s += v; q = fmaf(v, v, q);
      }
    sn[ni] = s; qn[ni] = q;
  }
#pragma unroll
  for (int ni = 0; ni < 2; ++ni) {
    sn[ni] += __shfl_xor(sn[ni], 16);
    sn[ni] += __shfl_xor(sn[ni], 32);
    qn[ni] += __shfl_xor(qn[ni], 16);
    qn[ni] += __shfl_xor(qn[ni], 32);
  }
  if (lane < 16) {
    float* dst = st2 + (blk & 15) * 256;
#pragma unroll
    for (int ni = 0; ni < 2; ++ni) {
      atomicAdd(&dst[wid * 32 + ni * 16 + lr], sn[ni]);
      atomicAdd(&dst[128 + wid * 32 + ni * 16 + lr], qn[ni]);
    }
  }
}

// ---------------- 7. bnout: BN2 from 16 striped stats + transpose to NCHW ----------
__global__ __launch_bounds__(256) void bnout_kernel(const ushort* __restrict__ O,
                                                    const float* __restrict__ st2,
                                                    const float* __restrict__ g2,
                                                    const float* __restrict__ bt2,
                                                    float* __restrict__ out) {
  __shared__ float tile[128 * 33];
  __shared__ float scs[128], shs[128];
  int blk = blockIdx.x;
  int uu = blk & 31, par = (blk >> 5) & 3, b = blk >> 7;
  int pu = par >> 1, pv = par & 1;
  int tid = threadIdx.x;
  if (tid < 128) {
    float s = 0.f, sq = 0.f;
#pragma unroll
    for (int c = 0; c < 16; ++c) {
      s += st2[c * 256 + tid];
      sq += st2[c * 256 + 128 + tid];
    }
    float mean = s / 65536.f;
    float var = sq / 65536.f - mean * mean;
    float sc = g2[tid] * rsqrtf(var + EPSV);
    scs[tid] = sc;
    shs[tid] = fmaf(-mean, sc, bt2[tid]);
  }
  __syncthreads();
#pragma unroll 4
  for (int it = 0; it < 16; ++it) {
    int idx = it * 256 + tid;
    int vv = idx >> 7, oc = idx & 127;
    float v = b2f(O[((size_t)(b * 4 + par) * 1024 + uu * 32 + vv) * 128 + oc]);
    tile[oc * 33 + vv] = fmaxf(fmaf(v, scs[oc], shs[oc]), 0.f);
  }
  __syncthreads();
#pragma unroll 4
  for (int it = 0; it < 16; ++it) {
    int idx = it * 256 + tid;
    int oc = idx >> 5, vv = idx & 31;
    out[((size_t)b * 128 + oc) * 4096 + (2 * uu + pu) * 64 + 2 * vv + pv] = tile[oc * 33 + vv];
  }
}

extern "C" void kernel_launch(void* const* d_in, const int* in_sizes, int n_in,
                              void* d_out, int out_size, void* d_ws, size_t ws_size,
                              hipStream_t stream) {
  const float* x     = (const float*)d_in[0];
  const float* w_off = (const float*)d_in[1];
  const float* b_off = (const float*)d_in[2];
  const float* w_dcn = (const float*)d_in[3];
  const float* b_dcn = (const float*)d_in[4];
  const float* g1    = (const float*)d_in[5];
  const float* bt1   = (const float*)d_in[6];
  const float* w_up  = (const float*)d_in[7];
  const float* g2    = (const float*)d_in[8];
  const float* bt2   = (const float*)d_in[9];
  float* ws  = (float*)d_ws;
  float* out = (float*)d_out;

  prep_xt_kernel<<<3508, 256, 0, stream>>>(x, w_off, w_dcn, w_up, ws);
  offconv_mfma_kernel<<<512, 256, 0, stream>>>((const __half*)(ws + XT),
                                               (const __half*)(ws + BOFF), ws + OFFB);
  deform_mfma_kernel<<<1024, 256, 0, stream>>>((const __half*)(ws + XT), ws + OFFB, b_off,
                                               (const __half*)(ws + BD), (ushort*)(ws + YP));
  yred_kernel<<<128, 256, 0, stream>>>((const ushort*)(ws + YP), b_dcn,
                                       (ushort*)(ws + YSUM), ws + ST1);
  ybn_kernel<<<1024, 256, 0, stream>>>((const ushort*)(ws + YSUM), ws + ST1, g1, bt1,
                                       (ushort*)(ws + YBN));
  deconv_mfma_kernel<<<1024, 256, 0, stream>>>((const ushort*)(ws + YBN),
                                               (const ushort*)(ws + BQ),
                                               (ushort*)(ws + OB), ws + ST2);
  bnout_kernel<<<2048, 256, 0, stream>>>((const ushort*)(ws + OB), ws + ST2, g2, bt2, out);
}